// Round 3
// baseline (18259.966 us; speedup 1.0000x reference)
//
#include <hip/hip_runtime.h>
#include <hip/hip_cooperative_groups.h>
#include <math.h>

namespace cg = cooperative_groups;

// Problem constants: L=512 (batch/spatial), T=96, C=H=150, K=5
#define LB     512
#define TSTEPS 96
#define CIN    150
#define HDIM   150
#define KW     5
#define CO3    450   // 3*H

// fast device math: v_exp_f32-based sigmoid / tanh (rel err ~2^-21)
__device__ __forceinline__ float fsigmoid(float x) {
    return __builtin_amdgcn_rcpf(1.f + __expf(-x));
}
__device__ __forceinline__ float ftanh(float x) {
    return fmaf(2.f, __builtin_amdgcn_rcpf(1.f + __expf(-2.f * x)), -1.f);
}

// ---------------------------------------------------------------------------
// xi conv (unchanged from round 2): xi[t][b][co] = bias[co] + sum_{k,ci}
//   X[b+k-2][t][ci] * Wi[k][ci][co];  X elem (b',t,ci) at src[b'*srcB+t*srcT+ci]
// xi layout (T,B,450). grid (32,96) x 256 thr; tid<225 owns co pair x 16 b rows.
// Measured: 445 us, VALUBusy 81%, ~74 TF (47% of fp32 peak).
// ---------------------------------------------------------------------------
__global__ __launch_bounds__(256) void xi_conv_kernel(
    const float* __restrict__ src, long srcB, long srcT,
    const float* __restrict__ Wi, const float* __restrict__ bias,
    float* __restrict__ xi)
{
    __shared__ __align__(16) float xsh[CIN][20];
    const int b0  = blockIdx.x * 16;
    const int t   = blockIdx.y;
    const int tid = threadIdx.x;

    for (int idx = tid; idx < 20 * CIN; idx += 256) {
        int row = idx / CIN;
        int ci  = idx - row * CIN;
        int bp  = b0 + row - 2;
        float v = 0.f;
        if (bp >= 0 && bp < LB) v = src[(long)bp * srcB + (long)t * srcT + ci];
        xsh[ci][row] = v;
    }
    __syncthreads();

    if (tid < 225) {
        const int co = 2 * tid;
        float acc0[16], acc1[16];
        #pragma unroll
        for (int b = 0; b < 16; ++b) { acc0[b] = 0.f; acc1[b] = 0.f; }

        for (int ci = 0; ci < CIN; ++ci) {
            float4 a0 = *(const float4*)&xsh[ci][0];
            float4 a1 = *(const float4*)&xsh[ci][4];
            float4 a2 = *(const float4*)&xsh[ci][8];
            float4 a3 = *(const float4*)&xsh[ci][12];
            float4 a4 = *(const float4*)&xsh[ci][16];
            float xr[20];
            xr[0]=a0.x; xr[1]=a0.y; xr[2]=a0.z; xr[3]=a0.w;
            xr[4]=a1.x; xr[5]=a1.y; xr[6]=a1.z; xr[7]=a1.w;
            xr[8]=a2.x; xr[9]=a2.y; xr[10]=a2.z; xr[11]=a2.w;
            xr[12]=a3.x; xr[13]=a3.y; xr[14]=a3.z; xr[15]=a3.w;
            xr[16]=a4.x; xr[17]=a4.y; xr[18]=a4.z; xr[19]=a4.w;

            #pragma unroll
            for (int k = 0; k < KW; ++k) {
                const float2 w = *(const float2*)&Wi[((long)(k * CIN + ci)) * CO3 + co];
                #pragma unroll
                for (int b = 0; b < 16; ++b) {
                    float x = xr[b + k];
                    acc0[b] = fmaf(w.x, x, acc0[b]);
                    acc1[b] = fmaf(w.y, x, acc1[b]);
                }
            }
        }

        const float2 bia = *(const float2*)&bias[co];
        float* xo = xi + ((long)t * LB + b0) * CO3 + co;
        #pragma unroll
        for (int b = 0; b < 16; ++b) {
            float2 o; o.x = acc0[b] + bia.x; o.y = acc1[b] + bia.y;
            *(float2*)&xo[(long)b * CO3] = o;
        }
    }
}

// ---------------------------------------------------------------------------
// Persistent GRU chain: 96 steps in ONE cooperative kernel, grid.sync per step.
// Grid 240 = 16 b-tiles (32 rows) x 15 j-tiles (10 j). Block 512 threads:
//   active tid<480: c = tid%30 -> (gate g = c/10, jl = c%10); grp = tid/30:
//   rgrp = grp&3 (8 rows each), cisub = grp>>2 (ci quarters 38/38/37/37).
// Per step: stage h(t-1) rows [b0-4,b0+36) transposed into LDS -> partial conv
// (acc[8] over ci quarter) -> LDS partial reduce -> gates -> write h(t).
// Weight traffic 21.6 MB/step (L2-resident); h stage 24 KB/block.
// h slice t elem (b,j) at ybase[t*yT + b*bS + j].
// ---------------------------------------------------------------------------
__global__ __launch_bounds__(512, 1) void gru_seq_kernel(
    const float* __restrict__ Wh,
    const float* __restrict__ xi,
    float* __restrict__ ybase,
    long yT, long bS)
{
    cg::grid_group grid = cg::this_grid();

    __shared__ __align__(16) float hsh[CIN][40];   // [ci][padded row], rows b0-4..b0+35
    __shared__ float part[4][32][30];              // [cisub][row_local][c]

    const int blk = blockIdx.x;          // 240
    const int bt  = blk / 15;
    const int jt  = blk - bt * 15;
    const int b0  = bt * 32;
    const int j0  = jt * 10;
    const int tid = threadIdx.x;

    const bool act  = (tid < 480);
    const int  c    = act ? tid % 30 : 0;
    const int  grp  = act ? tid / 30 : 0;
    const int  jl   = c % 10;
    const int  g    = c / 10;
    const int  rgrp = grp & 3;
    const int  cisub= grp >> 2;
    const int  co   = g * HDIM + j0 + jl;
    const int  ci0  = (cisub < 2) ? cisub * 38 : 76 + (cisub - 2) * 37;
    const int  nci  = (cisub < 2) ? 38 : 37;
    const int  base = rgrp * 8;                    // padded-row base of this thread's window
    const float* wcol = Wh + co;

    for (int t = 0; t < TSTEPS; ++t) {
        // ---- stage h(t-1) (zeros at t==0), transposed [ci][row] ----
        const float* hsrc = ybase + (long)(t - 1) * yT;
        for (int idx = tid; idx < 40 * CIN; idx += 512) {
            int row = idx / CIN;
            int ci  = idx - row * CIN;
            int gr  = b0 - 4 + row;
            float v = 0.f;
            if (t > 0 && gr >= 0 && gr < LB) v = hsrc[(long)gr * bS + ci];
            hsh[ci][row] = v;
        }
        __syncthreads();

        // ---- hh conv partials: acc[i] = sum_{k, ci in quarter} w_k * h[b0+base-4+ i+k+2][ci]
        if (act) {
            float acc[8] = {0.f,0.f,0.f,0.f,0.f,0.f,0.f,0.f};
            #pragma unroll 2
            for (int ci = ci0; ci < ci0 + nci; ++ci) {
                float4 a0 = *(const float4*)&hsh[ci][base];       // aligned b128
                float4 a1 = *(const float4*)&hsh[ci][base + 4];
                float4 a2 = *(const float4*)&hsh[ci][base + 8];
                float4 a3 = *(const float4*)&hsh[ci][base + 12];
                float w[16];
                w[0]=a0.x;  w[1]=a0.y;  w[2]=a0.z;  w[3]=a0.w;
                w[4]=a1.x;  w[5]=a1.y;  w[6]=a1.z;  w[7]=a1.w;
                w[8]=a2.x;  w[9]=a2.y;  w[10]=a2.z; w[11]=a2.w;
                w[12]=a3.x; w[13]=a3.y; w[14]=a3.z; w[15]=a3.w;
                #pragma unroll
                for (int k = 0; k < KW; ++k) {
                    float wk = wcol[(long)((k * CIN + ci)) * CO3];
                    #pragma unroll
                    for (int i = 0; i < 8; ++i)
                        acc[i] = fmaf(wk, w[i + k + 2], acc[i]);
                }
            }
            #pragma unroll
            for (int i = 0; i < 8; ++i) part[cisub][base + i][c] = acc[i];
        }
        __syncthreads();

        // ---- reduce partials + gates: 320 outputs (32 rows x 10 j) ----
        if (tid < 320) {
            int row = tid / 10;
            int j2  = tid - row * 10;
            float hr = part[0][row][j2]      + part[1][row][j2]
                     + part[2][row][j2]      + part[3][row][j2];
            float hz = part[0][row][10 + j2] + part[1][row][10 + j2]
                     + part[2][row][10 + j2] + part[3][row][10 + j2];
            float hn = part[0][row][20 + j2] + part[1][row][20 + j2]
                     + part[2][row][20 + j2] + part[3][row][20 + j2];
            int b = b0 + row;
            const float* xp = xi + ((long)t * LB + b) * CO3 + j0 + j2;
            float r  = fsigmoid(xp[0]        + hr);
            float z  = fsigmoid(xp[HDIM]     + hz);
            float n  = ftanh(fmaf(r, hn, xp[2 * HDIM]));
            float hp = hsh[j0 + j2][row + 4];              // h(t-1)[b][j] (zeros at t=0)
            ybase[(long)t * yT + (long)b * bS + j0 + j2] = fmaf(z, hp - n, n);
        }
        __threadfence();     // device-scope release before cross-XCD consume
        grid.sync();
    }
}

// ---------------------------------------------------------------------------
extern "C" void kernel_launch(void* const* d_in, const int* in_sizes, int n_in,
                              void* d_out, int out_size, void* d_ws, size_t ws_size,
                              hipStream_t stream) {
    const float* xs  = (const float*)d_in[0];
    const float* Wi0 = (const float*)d_in[1];
    const float* bi0 = (const float*)d_in[2];
    const float* Wh0 = (const float*)d_in[3];
    const float* Wi1 = (const float*)d_in[4];
    const float* bi1 = (const float*)d_in[5];
    const float* Wh1 = (const float*)d_in[6];
    float* out = (float*)d_out;

    // ws: xi (96*512*450 f, 88.5 MB) + ys0 (96*512*150 f, 29.5 MB)
    float* xi  = (float*)d_ws;
    float* ys0 = xi + (size_t)TSTEPS * LB * CO3;

    dim3 gxi(32, TSTEPS);

    // ---- layer 0 ----
    hipLaunchKernelGGL(xi_conv_kernel, gxi, dim3(256), 0, stream,
                       xs, (long)(TSTEPS * CIN), (long)CIN, Wi0, bi0, xi);
    {
        const float* Wh = Wh0; const float* xip = xi; float* yb = ys0;
        long yT = (long)LB * HDIM;  // ys0 (T,B,H)
        long bS = (long)HDIM;
        void* args[] = { (void*)&Wh, (void*)&xip, (void*)&yb, (void*)&yT, (void*)&bS };
        hipLaunchCooperativeKernel((void*)gru_seq_kernel, dim3(240), dim3(512),
                                   args, 0, stream);
    }

    // ---- layer 1 ----
    hipLaunchKernelGGL(xi_conv_kernel, gxi, dim3(256), 0, stream,
                       ys0, (long)HDIM, (long)(LB * HDIM), Wi1, bi1, xi);
    {
        const float* Wh = Wh1; const float* xip = xi; float* yb = out;
        long yT = (long)HDIM;            // out (B,T,H): t slice offset = t*H
        long bS = (long)(TSTEPS * HDIM); // b stride = T*H
        void* args[] = { (void*)&Wh, (void*)&xip, (void*)&yb, (void*)&yT, (void*)&bS };
        hipLaunchCooperativeKernel((void*)gru_seq_kernel, dim3(240), dim3(512),
                                   args, 0, stream);
    }
}

// Round 7
// 4218.357 us; speedup vs baseline: 4.3287x; 4.3287x over previous
//
#include <hip/hip_runtime.h>
#include <math.h>

// Problem constants: L=512 (batch/spatial), T=96, C=H=150, K=5
#define LB     512
#define TSTEPS 96
#define CIN    150
#define HDIM   150
#define KW     5
#define CO3    450   // 3*H
// gru tiling
#define NBT    16    // b-tiles
#define NJT    15    // j-tiles
#define BROWS  32    // rows per b-tile
#define JW     10    // j per j-tile (30 co = 3 gates x 10 j)
#define NCH    15    // ci chunks
#define CICH   10    // ci per chunk
#define HROWS  36    // staged rows = 32 + 2x2 halo
#define HPAD   152   // LDS row stride (floats): 608 B, 8B-aligned b64 reads

// fast device math: v_exp_f32-based sigmoid / tanh (rel err ~2^-21)
__device__ __forceinline__ float fsigmoid(float x) {
    return __builtin_amdgcn_rcpf(1.f + __expf(-x));
}
__device__ __forceinline__ float ftanh(float x) {
    return fmaf(2.f, __builtin_amdgcn_rcpf(1.f + __expf(-2.f * x)), -1.f);
}

// coherent (agent-scope) scalar ops for cross-XCD h traffic; relaxed ordering —
// ordering is provided by __syncthreads' vmcnt(0) drain on the producer side.
__device__ __forceinline__ float h_load(const float* p) {
    return __hip_atomic_load(p, __ATOMIC_RELAXED, __HIP_MEMORY_SCOPE_AGENT);
}
__device__ __forceinline__ void h_store(float* p, float v) {
    __hip_atomic_store(p, v, __ATOMIC_RELAXED, __HIP_MEMORY_SCOPE_AGENT);
}

// ---------------------------------------------------------------------------
// xi conv (unchanged; measured 445 us, VALUBusy 81%, ~74 TF)
// xi[t][b][co] = bias[co] + sum_{k,ci} X[b+k-2][t][ci] * Wi[k][ci][co]
// X elem (b',t,ci) at src[b'*srcB + t*srcT + ci]; xi layout (T,B,450).
// ---------------------------------------------------------------------------
__global__ __launch_bounds__(256) void xi_conv_kernel(
    const float* __restrict__ src, long srcB, long srcT,
    const float* __restrict__ Wi, const float* __restrict__ bias,
    float* __restrict__ xi)
{
    __shared__ __align__(16) float xsh[CIN][20];
    const int b0  = blockIdx.x * 16;
    const int t   = blockIdx.y;
    const int tid = threadIdx.x;

    for (int idx = tid; idx < 20 * CIN; idx += 256) {
        int row = idx / CIN;
        int ci  = idx - row * CIN;
        int bp  = b0 + row - 2;
        float v = 0.f;
        if (bp >= 0 && bp < LB) v = src[(long)bp * srcB + (long)t * srcT + ci];
        xsh[ci][row] = v;
    }
    __syncthreads();

    if (tid < 225) {
        const int co = 2 * tid;
        float acc0[16], acc1[16];
        #pragma unroll
        for (int b = 0; b < 16; ++b) { acc0[b] = 0.f; acc1[b] = 0.f; }

        for (int ci = 0; ci < CIN; ++ci) {
            float4 a0 = *(const float4*)&xsh[ci][0];
            float4 a1 = *(const float4*)&xsh[ci][4];
            float4 a2 = *(const float4*)&xsh[ci][8];
            float4 a3 = *(const float4*)&xsh[ci][12];
            float4 a4 = *(const float4*)&xsh[ci][16];
            float xr[20];
            xr[0]=a0.x; xr[1]=a0.y; xr[2]=a0.z; xr[3]=a0.w;
            xr[4]=a1.x; xr[5]=a1.y; xr[6]=a1.z; xr[7]=a1.w;
            xr[8]=a2.x; xr[9]=a2.y; xr[10]=a2.z; xr[11]=a2.w;
            xr[12]=a3.x; xr[13]=a3.y; xr[14]=a3.z; xr[15]=a3.w;
            xr[16]=a4.x; xr[17]=a4.y; xr[18]=a4.z; xr[19]=a4.w;

            #pragma unroll
            for (int k = 0; k < KW; ++k) {
                const float2 w = *(const float2*)&Wi[((long)(k * CIN + ci)) * CO3 + co];
                #pragma unroll
                for (int b = 0; b < 16; ++b) {
                    float x = xr[b + k];
                    acc0[b] = fmaf(w.x, x, acc0[b]);
                    acc1[b] = fmaf(w.y, x, acc1[b]);
                }
            }
        }

        const float2 bia = *(const float2*)&bias[co];
        float* xo = xi + ((long)t * LB + b0) * CO3 + co;
        #pragma unroll
        for (int b = 0; b < 16; ++b) {
            float2 o; o.x = acc0[b] + bia.x; o.y = acc1[b] + bia.y;
            *(float2*)&xo[(long)b * CO3] = o;
        }
    }
}

// ---------------------------------------------------------------------------
// Persistent GRU pipeline, NO global barrier (round-3's grid.sync cost 90us/step).
// Grid 240 = 16 bt x 15 jt, block 512 (8 waves, 1 block/CU).
// Thread (tid<450): c = tid%30 (gate g=c/10, jl=c%10), ch = tid/30 (ci chunk).
// Weights w[5][10] live in VGPRs for all 96 steps. Per step:
//   poll cnt[bt-1..bt+1] >= 15*t  ->  stage h(t-1)[b0-2..b0+34)x150 into LDS
//   -> conv: acc[32] over own (co, ci-chunk), b64 broadcast h reads
//   -> LDS partial reduce (15 chunks) + gates -> coherent h(t) store
//   -> relaxed agent fetch_add(cnt[bt]).
// h slice t elem (b,j) at ybase[t*yT + b*bS + j]; distinct per t => pure DAG.
// ---------------------------------------------------------------------------
__global__ __launch_bounds__(512, 1) void gru_seq_kernel(
    const float* __restrict__ Wh,
    const float* __restrict__ xi,
    float* __restrict__ ybase,
    long yT, long bS,
    int* __restrict__ cnt)
{
    __shared__ __align__(16) float hsh[HROWS][HPAD];      // 21.9 KB [row][ci]
    __shared__ float part[NCH][BROWS][3 * JW];            // 57.6 KB

    const int blk = blockIdx.x;
    const int bt  = blk / NJT;
    const int jt  = blk - bt * NJT;
    const int b0  = bt * BROWS;
    const int j0  = jt * JW;
    const int tid = threadIdx.x;

    const bool act = (tid < NCH * 3 * JW);   // 450
    const int  c   = tid % (3 * JW);
    const int  ch  = tid / (3 * JW);
    const int  g   = c / JW;
    const int  jl  = c - g * JW;
    const int  co  = g * HDIM + j0 + jl;
    const int  ci0 = ch * CICH;

    const int lo = (bt > 0) ? bt - 1 : 0;
    const int hi = (bt < NBT - 1) ? bt + 1 : NBT - 1;

    // ---- one-time: weights into registers (fully unrolled -> VGPRs) ----
    float w[KW][CICH];
    if (act) {
        #pragma unroll
        for (int k = 0; k < KW; ++k)
            #pragma unroll
            for (int i = 0; i < CICH; ++i)
                w[k][i] = Wh[((long)(k * CIN + ci0 + i)) * CO3 + co];
    }

    for (int t = 0; t < TSTEPS; ++t) {
        // ---- wait for producers of h(t-1) (halo +-2 rows -> bt-1..bt+1) ----
        if (t > 0 && tid == 0) {
            const int tgt = NJT * t;
            for (int x = lo; x <= hi; ++x) {
                while (__hip_atomic_load(&cnt[x], __ATOMIC_RELAXED,
                                         __HIP_MEMORY_SCOPE_AGENT) < tgt)
                    __builtin_amdgcn_s_sleep(1);
            }
        }
        __syncthreads();

        // ---- stage h(t-1) rows b0-2..b0+33 into LDS [row][ci] ----
        const float* hsrc = ybase + (long)(t - 1) * yT;
        for (int idx = tid; idx < HROWS * CIN; idx += 512) {
            int row = idx / CIN;
            int ci  = idx - row * CIN;
            int gr  = b0 - 2 + row;
            float v = 0.f;
            if (t > 0 && gr >= 0 && gr < LB)
                v = h_load(&hsrc[(long)gr * bS + ci]);
            hsh[row][ci] = v;
        }
        __syncthreads();

        // ---- conv: acc[r] += w[k][i] * h[b0 + r + k - 2][ci0+i] ----
        if (act) {
            float acc[BROWS];
            #pragma unroll
            for (int r = 0; r < BROWS; ++r) acc[r] = 0.f;
            #pragma unroll
            for (int p = 0; p < CICH / 2; ++p) {
                #pragma unroll
                for (int row = 0; row < HROWS; ++row) {
                    // staged row 'row' = global b0-2+row; feeds r = row - k
                    float2 h2 = *(const float2*)&hsh[row][ci0 + 2 * p];
                    #pragma unroll
                    for (int k = 0; k < KW; ++k) {
                        const int r = row - k;
                        if (r >= 0 && r < BROWS) {
                            acc[r] = fmaf(w[k][2 * p],     h2.x, acc[r]);
                            acc[r] = fmaf(w[k][2 * p + 1], h2.y, acc[r]);
                        }
                    }
                }
            }
            #pragma unroll
            for (int r = 0; r < BROWS; ++r) part[ch][r][c] = acc[r];
        }
        __syncthreads();

        // ---- reduce 15 chunks + gates + coherent store ----
        if (tid < BROWS * JW) {            // 320
            const int row = tid / JW;
            const int j2  = tid - row * JW;
            float hr = 0.f, hz = 0.f, hn = 0.f;
            #pragma unroll
            for (int s = 0; s < NCH; ++s) {
                hr += part[s][row][j2];
                hz += part[s][row][JW + j2];
                hn += part[s][row][2 * JW + j2];
            }
            const int b = b0 + row;
            const float* xp = xi + ((long)t * LB + b) * CO3 + j0 + j2;
            float r  = fsigmoid(xp[0]        + hr);
            float z  = fsigmoid(xp[HDIM]     + hz);
            float n  = ftanh(fmaf(r, hn, xp[2 * HDIM]));
            float hp = hsh[row + 2][j0 + j2];        // h(t-1)[b][j], zeros at t=0
            h_store(&ybase[(long)t * yT + (long)b * bS + j0 + j2],
                    fmaf(z, hp - n, n));
        }
        __syncthreads();   // drains vmcnt(0): h(t) stores acked before flag add

        if (tid == 0)
            __hip_atomic_fetch_add(&cnt[bt], 1, __ATOMIC_RELAXED,
                                   __HIP_MEMORY_SCOPE_AGENT);
    }
}

// ---------------------------------------------------------------------------
__global__ void zero_cnt_kernel(int* cnt) {
    if (threadIdx.x < 64) cnt[threadIdx.x] = 0;
}

// ---------------------------------------------------------------------------
extern "C" void kernel_launch(void* const* d_in, const int* in_sizes, int n_in,
                              void* d_out, int out_size, void* d_ws, size_t ws_size,
                              hipStream_t stream) {
    const float* xs  = (const float*)d_in[0];
    const float* Wi0 = (const float*)d_in[1];
    const float* bi0 = (const float*)d_in[2];
    const float* Wh0 = (const float*)d_in[3];
    const float* Wi1 = (const float*)d_in[4];
    const float* bi1 = (const float*)d_in[5];
    const float* Wh1 = (const float*)d_in[6];
    float* out = (float*)d_out;

    // ws layout: [cnt 64 ints | xi 96*512*450 f | ys0 96*512*150 f]  (~118 MB)
    int*   cnt = (int*)d_ws;
    float* xi  = (float*)((char*)d_ws + 256);
    float* ys0 = xi + (size_t)TSTEPS * LB * CO3;

    hipLaunchKernelGGL(zero_cnt_kernel, dim3(1), dim3(64), 0, stream, cnt);

    dim3 gxi(32, TSTEPS);

    // ---- layer 0 ----
    hipLaunchKernelGGL(xi_conv_kernel, gxi, dim3(256), 0, stream,
                       xs, (long)(TSTEPS * CIN), (long)CIN, Wi0, bi0, xi);
    {
        const float* Wh = Wh0; const float* xip = xi; float* yb = ys0;
        long yT = (long)LB * HDIM;   // ys0 (T,B,H)
        long bS = (long)HDIM;
        int* c0 = cnt;
        void* args[] = { (void*)&Wh, (void*)&xip, (void*)&yb,
                         (void*)&yT, (void*)&bS, (void*)&c0 };
        hipLaunchCooperativeKernel((void*)gru_seq_kernel, dim3(NBT * NJT),
                                   dim3(512), args, 0, stream);
    }

    // ---- layer 1 ----
    hipLaunchKernelGGL(xi_conv_kernel, gxi, dim3(256), 0, stream,
                       ys0, (long)HDIM, (long)(LB * HDIM), Wi1, bi1, xi);
    {
        const float* Wh = Wh1; const float* xip = xi; float* yb = out;
        long yT = (long)HDIM;             // out (B,T,H): t slice offset = t*H
        long bS = (long)(TSTEPS * HDIM);  // b stride = T*H
        int* c1 = cnt + 16;
        void* args[] = { (void*)&Wh, (void*)&xip, (void*)&yb,
                         (void*)&yT, (void*)&bS, (void*)&c1 };
        hipLaunchCooperativeKernel((void*)gru_seq_kernel, dim3(NBT * NJT),
                                   dim3(512), args, 0, stream);
    }
}

// Round 8
// 2777.906 us; speedup vs baseline: 6.5733x; 1.5185x over previous
//
#include <hip/hip_runtime.h>
#include <math.h>

// Problem constants: L=512 (batch/spatial), T=96, C=H=150, K=5
#define LB     512
#define TSTEPS 96
#define CIN    150
#define HDIM   150
#define KW     5
#define CO3    450   // 3*H
// gru tiling
#define NBT    16    // b-tiles
#define NJT    15    // j-tiles
#define BROWS  32    // rows per b-tile
#define JW     10    // j per j-tile (30 co = 3 gates x 10 j)
#define NCH    15    // ci chunks
#define CICH   10    // ci per chunk
#define HROWS  36    // staged rows = 32 + 2x2 halo
#define HPAD   152   // LDS row stride (floats): 608 B, 8B-aligned b64 reads
#define CNTSTR 32    // ints per counter slot (128 B) — kill line contention
#define STITER 11    // ceil(HROWS*CIN / 512)

// fast device math: v_exp_f32-based sigmoid / tanh (rel err ~2^-21)
__device__ __forceinline__ float fsigmoid(float x) {
    return __builtin_amdgcn_rcpf(1.f + __expf(-x));
}
__device__ __forceinline__ float ftanh(float x) {
    return fmaf(2.f, __builtin_amdgcn_rcpf(1.f + __expf(-2.f * x)), -1.f);
}

// coherent (agent-scope) scalar ops for cross-XCD h traffic; relaxed ordering —
// ordering is provided by __syncthreads' vmcnt(0) drain on the producer side.
__device__ __forceinline__ float h_load(const float* p) {
    return __hip_atomic_load(p, __ATOMIC_RELAXED, __HIP_MEMORY_SCOPE_AGENT);
}
__device__ __forceinline__ void h_store(float* p, float v) {
    __hip_atomic_store(p, v, __ATOMIC_RELAXED, __HIP_MEMORY_SCOPE_AGENT);
}

// ---------------------------------------------------------------------------
// xi conv (unchanged; measured 445 us, VALUBusy 81%, ~74 TF)
// ---------------------------------------------------------------------------
__global__ __launch_bounds__(256) void xi_conv_kernel(
    const float* __restrict__ src, long srcB, long srcT,
    const float* __restrict__ Wi, const float* __restrict__ bias,
    float* __restrict__ xi)
{
    __shared__ __align__(16) float xsh[CIN][20];
    const int b0  = blockIdx.x * 16;
    const int t   = blockIdx.y;
    const int tid = threadIdx.x;

    for (int idx = tid; idx < 20 * CIN; idx += 256) {
        int row = idx / CIN;
        int ci  = idx - row * CIN;
        int bp  = b0 + row - 2;
        float v = 0.f;
        if (bp >= 0 && bp < LB) v = src[(long)bp * srcB + (long)t * srcT + ci];
        xsh[ci][row] = v;
    }
    __syncthreads();

    if (tid < 225) {
        const int co = 2 * tid;
        float acc0[16], acc1[16];
        #pragma unroll
        for (int b = 0; b < 16; ++b) { acc0[b] = 0.f; acc1[b] = 0.f; }

        for (int ci = 0; ci < CIN; ++ci) {
            float4 a0 = *(const float4*)&xsh[ci][0];
            float4 a1 = *(const float4*)&xsh[ci][4];
            float4 a2 = *(const float4*)&xsh[ci][8];
            float4 a3 = *(const float4*)&xsh[ci][12];
            float4 a4 = *(const float4*)&xsh[ci][16];
            float xr[20];
            xr[0]=a0.x; xr[1]=a0.y; xr[2]=a0.z; xr[3]=a0.w;
            xr[4]=a1.x; xr[5]=a1.y; xr[6]=a1.z; xr[7]=a1.w;
            xr[8]=a2.x; xr[9]=a2.y; xr[10]=a2.z; xr[11]=a2.w;
            xr[12]=a3.x; xr[13]=a3.y; xr[14]=a3.z; xr[15]=a3.w;
            xr[16]=a4.x; xr[17]=a4.y; xr[18]=a4.z; xr[19]=a4.w;

            #pragma unroll
            for (int k = 0; k < KW; ++k) {
                const float2 w = *(const float2*)&Wi[((long)(k * CIN + ci)) * CO3 + co];
                #pragma unroll
                for (int b = 0; b < 16; ++b) {
                    float x = xr[b + k];
                    acc0[b] = fmaf(w.x, x, acc0[b]);
                    acc1[b] = fmaf(w.y, x, acc1[b]);
                }
            }
        }

        const float2 bia = *(const float2*)&bias[co];
        float* xo = xi + ((long)t * LB + b0) * CO3 + co;
        #pragma unroll
        for (int b = 0; b < 16; ++b) {
            float2 o; o.x = acc0[b] + bia.x; o.y = acc1[b] + bia.y;
            *(float2*)&xo[(long)b * CO3] = o;
        }
    }
}

// ---------------------------------------------------------------------------
// Persistent GRU pipeline (round-7 measured 17.9 us/step, VALUBusy 34%).
// This round: (1) unrolled staging (loads all in flight), (2) early xi
// prefetch, (3) padded counters + parallel 3-way poll.
// ---------------------------------------------------------------------------
__global__ __launch_bounds__(512, 1) void gru_seq_kernel(
    const float* __restrict__ Wh,
    const float* __restrict__ xi,
    float* __restrict__ ybase,
    long yT, long bS,
    int* __restrict__ cnt)
{
    __shared__ __align__(16) float hsh[HROWS][HPAD];      // 21.9 KB [row][ci]
    __shared__ float part[NCH][BROWS][3 * JW];            // 57.6 KB

    const int blk = blockIdx.x;
    const int bt  = blk / NJT;
    const int jt  = blk - bt * NJT;
    const int b0  = bt * BROWS;
    const int j0  = jt * JW;
    const int tid = threadIdx.x;

    const bool act = (tid < NCH * 3 * JW);   // 450 conv threads
    const int  c   = tid % (3 * JW);
    const int  ch  = tid / (3 * JW);
    const int  g   = c / JW;
    const int  jl  = c - g * JW;
    const int  co  = g * HDIM + j0 + jl;
    const int  ci0 = ch * CICH;

    const bool gthr = (tid < BROWS * JW);    // 320 gate threads
    const int  grow = tid / JW;
    const int  gj   = tid - grow * JW;

    // ---- one-time: weights into registers ----
    float w[KW][CICH];
    if (act) {
        #pragma unroll
        for (int k = 0; k < KW; ++k)
            #pragma unroll
            for (int i = 0; i < CICH; ++i)
                w[k][i] = Wh[((long)(k * CIN + ci0 + i)) * CO3 + co];
    }

    for (int t = 0; t < TSTEPS; ++t) {
        // ---- wait for producers of h(t-1): 3 counters polled in parallel ----
        if (t > 0 && tid < 3) {
            int x = bt - 1 + tid;
            if (x >= 0 && x < NBT) {
                const int tgt = NJT * t;
                while (__hip_atomic_load(&cnt[x * CNTSTR], __ATOMIC_RELAXED,
                                         __HIP_MEMORY_SCOPE_AGENT) < tgt)
                    __builtin_amdgcn_s_sleep(1);
            }
        }
        __syncthreads();

        // ---- xi prefetch FIRST (longest-latency loads, consumed in gates) ----
        float pxr = 0.f, pxz = 0.f, pxn = 0.f;
        if (gthr) {
            const float* xp = xi + ((long)t * LB + b0 + grow) * CO3 + j0 + gj;
            pxr = xp[0];
            pxz = xp[HDIM];
            pxn = xp[2 * HDIM];
        }

        // ---- stage h(t-1): fully unrolled, all loads in flight together ----
        if (t > 0) {
            const float* hsrc = ybase + (long)(t - 1) * yT;
            float v[STITER];
            int   rw[STITER], cv[STITER];
            bool  ok[STITER];
            #pragma unroll
            for (int it = 0; it < STITER; ++it) {
                int idx = tid + it * 512;
                int row = idx / CIN;
                int ci  = idx - row * CIN;
                int gr  = b0 - 2 + row;
                ok[it]  = (idx < HROWS * CIN) && (gr >= 0) && (gr < LB);
                int grc = gr < 0 ? 0 : (gr >= LB - 1 ? LB - 1 : gr);
                v[it]   = h_load(&hsrc[(long)grc * bS + ci]);  // clamped = always valid
                rw[it]  = row; cv[it] = ci;
            }
            #pragma unroll
            for (int it = 0; it < STITER; ++it) {
                int idx = tid + it * 512;
                if (idx < HROWS * CIN)
                    hsh[rw[it]][cv[it]] = ok[it] ? v[it] : 0.f;
            }
        } else {
            #pragma unroll
            for (int it = 0; it < STITER; ++it) {
                int idx = tid + it * 512;
                if (idx < HROWS * CIN) hsh[idx / CIN][idx % CIN] = 0.f;
            }
        }
        __syncthreads();

        // ---- conv: acc[r] += w[k][i] * h[b0 + r + k - 2][ci0+i] ----
        if (act) {
            float acc[BROWS];
            #pragma unroll
            for (int r = 0; r < BROWS; ++r) acc[r] = 0.f;
            #pragma unroll
            for (int p = 0; p < CICH / 2; ++p) {
                #pragma unroll
                for (int row = 0; row < HROWS; ++row) {
                    float2 h2 = *(const float2*)&hsh[row][ci0 + 2 * p];
                    #pragma unroll
                    for (int k = 0; k < KW; ++k) {
                        const int r = row - k;
                        if (r >= 0 && r < BROWS) {
                            acc[r] = fmaf(w[k][2 * p],     h2.x, acc[r]);
                            acc[r] = fmaf(w[k][2 * p + 1], h2.y, acc[r]);
                        }
                    }
                }
            }
            #pragma unroll
            for (int r = 0; r < BROWS; ++r) part[ch][r][c] = acc[r];
        }
        __syncthreads();

        // ---- reduce 15 chunks + gates (prefetched xi) + coherent store ----
        if (gthr) {
            float hr = 0.f, hz = 0.f, hn = 0.f;
            #pragma unroll
            for (int s = 0; s < NCH; ++s) {
                hr += part[s][grow][gj];
                hz += part[s][grow][JW + gj];
                hn += part[s][grow][2 * JW + gj];
            }
            const int b = b0 + grow;
            float r  = fsigmoid(pxr + hr);
            float z  = fsigmoid(pxz + hz);
            float n  = ftanh(fmaf(r, hn, pxn));
            float hp = hsh[grow + 2][j0 + gj];       // h(t-1)[b][j], zeros at t=0
            h_store(&ybase[(long)t * yT + (long)b * bS + j0 + gj],
                    fmaf(z, hp - n, n));
        }
        __syncthreads();   // drains vmcnt(0): h(t) stores acked before flag add

        if (tid == 0)
            __hip_atomic_fetch_add(&cnt[bt * CNTSTR], 1, __ATOMIC_RELAXED,
                                   __HIP_MEMORY_SCOPE_AGENT);
    }
}

// ---------------------------------------------------------------------------
__global__ void zero_cnt_kernel(int* cnt) {
    for (int i = threadIdx.x; i < 2 * NBT * CNTSTR; i += 256) cnt[i] = 0;
}

// ---------------------------------------------------------------------------
extern "C" void kernel_launch(void* const* d_in, const int* in_sizes, int n_in,
                              void* d_out, int out_size, void* d_ws, size_t ws_size,
                              hipStream_t stream) {
    const float* xs  = (const float*)d_in[0];
    const float* Wi0 = (const float*)d_in[1];
    const float* bi0 = (const float*)d_in[2];
    const float* Wh0 = (const float*)d_in[3];
    const float* Wi1 = (const float*)d_in[4];
    const float* bi1 = (const float*)d_in[5];
    const float* Wh1 = (const float*)d_in[6];
    float* out = (float*)d_out;

    // ws layout: [cnt 2*16*128B = 4 KB | xi 88.5 MB | ys0 29.5 MB]
    int*   cnt = (int*)d_ws;
    float* xi  = (float*)((char*)d_ws + 4096);
    float* ys0 = xi + (size_t)TSTEPS * LB * CO3;

    hipLaunchKernelGGL(zero_cnt_kernel, dim3(1), dim3(256), 0, stream, cnt);

    dim3 gxi(32, TSTEPS);

    // ---- layer 0 ----
    hipLaunchKernelGGL(xi_conv_kernel, gxi, dim3(256), 0, stream,
                       xs, (long)(TSTEPS * CIN), (long)CIN, Wi0, bi0, xi);
    {
        const float* Wh = Wh0; const float* xip = xi; float* yb = ys0;
        long yT = (long)LB * HDIM;   // ys0 (T,B,H)
        long bS = (long)HDIM;
        int* c0 = cnt;
        void* args[] = { (void*)&Wh, (void*)&xip, (void*)&yb,
                         (void*)&yT, (void*)&bS, (void*)&c0 };
        hipLaunchCooperativeKernel((void*)gru_seq_kernel, dim3(NBT * NJT),
                                   dim3(512), args, 0, stream);
    }

    // ---- layer 1 ----
    hipLaunchKernelGGL(xi_conv_kernel, gxi, dim3(256), 0, stream,
                       ys0, (long)HDIM, (long)(LB * HDIM), Wi1, bi1, xi);
    {
        const float* Wh = Wh1; const float* xip = xi; float* yb = out;
        long yT = (long)HDIM;             // out (B,T,H): t slice offset = t*H
        long bS = (long)(TSTEPS * HDIM);  // b stride = T*H
        int* c1 = cnt + NBT * CNTSTR;
        void* args[] = { (void*)&Wh, (void*)&xip, (void*)&yb,
                         (void*)&yT, (void*)&bS, (void*)&c1 };
        hipLaunchCooperativeKernel((void*)gru_seq_kernel, dim3(NBT * NJT),
                                   dim3(512), args, 0, stream);
    }
}